// Round 1
// baseline (247.809 us; speedup 1.0000x reference)
//
#include <hip/hip_runtime.h>
#include <hip/hip_bf16.h>

#define BB    8
#define TT    2048
#define CC    512
#define NHEAD 8
#define AATT  512
#define NCHUNK 16
#define CLEN   128   // TT / NCHUNK

typedef __attribute__((ext_vector_type(8))) short short8;
typedef __attribute__((ext_vector_type(4))) float f32x4;

__device__ inline unsigned short f2bf(float f) {
    __hip_bfloat16 h = __float2bfloat16(f);
    return *reinterpret_cast<unsigned short*>(&h);
}

// ---------------- weight fp32 -> bf16 (262144 elems, 4 per thread) ----------------
__global__ void convert_bf16(const float* __restrict__ src, unsigned short* __restrict__ dst) {
    int i = blockIdx.x * 256 + threadIdx.x;          // group of 4
    float4 v = *(const float4*)(src + (size_t)i * 4);
    union { unsigned short u[4]; uint2 p; } pk;
    pk.u[0] = f2bf(v.x); pk.u[1] = f2bf(v.y); pk.u[2] = f2bf(v.z); pk.u[3] = f2bf(v.w);
    *(uint2*)(dst + (size_t)i * 4) = pk.p;
}

// ---------------- time-shift mix: out = x*tm + x[t-1]*(1-tm), bf16 ----------------
__global__ void mix_kernel(const float* __restrict__ x, const float* __restrict__ tm,
                           unsigned short* __restrict__ out) {
    int i   = blockIdx.x * 256 + threadIdx.x;        // group of 4 channels
    int c4  = (i & (CC / 4 - 1)) << 2;
    int row = i >> 7;                                // b*T + t
    int t   = row & (TT - 1);
    float4 xv = *(const float4*)(x + (size_t)row * CC + c4);
    float4 xp = make_float4(0.f, 0.f, 0.f, 0.f);
    if (t != 0) xp = *(const float4*)(x + (size_t)(row - 1) * CC + c4);
    float4 tv = *(const float4*)(tm + c4);
    union { unsigned short u[4]; uint2 p; } pk;
    pk.u[0] = f2bf(xv.x * tv.x + xp.x * (1.f - tv.x));
    pk.u[1] = f2bf(xv.y * tv.y + xp.y * (1.f - tv.y));
    pk.u[2] = f2bf(xv.z * tv.z + xp.z * (1.f - tv.z));
    pk.u[3] = f2bf(xv.w * tv.w + xp.w * (1.f - tv.w));
    *(uint2*)(out + (size_t)row * CC + c4) = pk.p;
}

// ---------------- GEMM: C[m,n] = sum_k A[m,k]*W[n,k] + epilogue ----------------
// MODE 0: exp(clip(x+b,-60,30))  1: x+b  2: sigmoid(x+b)  3: (x+b)*gamma[t]
template <int MODE>
__launch_bounds__(256)
__global__ void gemm_bt(const unsigned short* __restrict__ Abf,
                        const unsigned short* __restrict__ Wbf,
                        const float* __restrict__ bias,
                        float* __restrict__ out,
                        const float* __restrict__ gamma) {
    __shared__ short As[128 * 72];
    __shared__ short Bs[128 * 72];
    const int tid  = threadIdx.x;
    const int lane = tid & 63;
    const int wv   = tid >> 6;
    const int wm   = (wv >> 1) << 6;
    const int wn   = (wv & 1) << 6;
    const int mBlk = blockIdx.y << 7;
    const int nBlk = blockIdx.x << 7;
    const int r16  = lane & 15, q = lane >> 4;

    f32x4 acc[4][4];
#pragma unroll
    for (int a = 0; a < 4; ++a)
#pragma unroll
        for (int b = 0; b < 4; ++b) acc[a][b] = (f32x4){0.f, 0.f, 0.f, 0.f};

    for (int k0 = 0; k0 < 512; k0 += 64) {
#pragma unroll
        for (int i = 0; i < 4; ++i) {
            int cidx = i * 256 + tid;
            int row = cidx >> 3, qc = cidx & 7;
            *(int4*)(&As[row * 72 + qc * 8]) =
                *(const int4*)(Abf + (size_t)(mBlk + row) * 512 + k0 + qc * 8);
            *(int4*)(&Bs[row * 72 + qc * 8]) =
                *(const int4*)(Wbf + (size_t)(nBlk + row) * 512 + k0 + qc * 8);
        }
        __syncthreads();
#pragma unroll
        for (int s = 0; s < 2; ++s) {
            short8 af[4], bfr[4];
#pragma unroll
            for (int mt = 0; mt < 4; ++mt)
                af[mt] = *(const short8*)(&As[(wm + mt * 16 + r16) * 72 + s * 32 + q * 8]);
#pragma unroll
            for (int nt = 0; nt < 4; ++nt)
                bfr[nt] = *(const short8*)(&Bs[(wn + nt * 16 + r16) * 72 + s * 32 + q * 8]);
#pragma unroll
            for (int mt = 0; mt < 4; ++mt)
#pragma unroll
                for (int nt = 0; nt < 4; ++nt)
                    acc[mt][nt] = __builtin_amdgcn_mfma_f32_16x16x32_bf16(
                        af[mt], bfr[nt], acc[mt][nt], 0, 0, 0);
        }
        __syncthreads();
    }

#pragma unroll
    for (int mt = 0; mt < 4; ++mt) {
#pragma unroll
        for (int nt = 0; nt < 4; ++nt) {
            int col = nBlk + wn + nt * 16 + r16;
            float bv = bias[col];
#pragma unroll
            for (int i = 0; i < 4; ++i) {
                int row = mBlk + wm + mt * 16 + (q << 2) + i;
                float v = acc[mt][nt][i] + bv;
                if (MODE == 0) v = __expf(fminf(fmaxf(v, -60.f), 30.f));
                else if (MODE == 2) v = 1.f / (1.f + __expf(-v));
                else if (MODE == 3) v = v * gamma[row & (TT - 1)];
                out[(size_t)row * 512 + col] = v;
            }
        }
    }
}

// ---------------- scan phase A: per-chunk local reductions ----------------
__global__ void scanA(const float* __restrict__ kbuf, const float* __restrict__ vbuf,
                      const float* __restrict__ tw, const float* __restrict__ alpha,
                      float* __restrict__ Sloc, float* __restrict__ Kloc) {
    int tid = threadIdx.x;
    int bid = blockIdx.x;                 // b*32 + j*2 + ab
    int ab = bid & 1, j = (bid >> 1) & 15, b = bid >> 5;
    int a = ab * 256 + tid;
    int h = a >> 6;
    float r = tw[h * TT + TT - 2];        // exp(-d_h)
    int t0 = j * CLEN;
    const float* kp = kbuf + ((size_t)(b * TT + t0)) * 512 + a;
    const float* vp = vbuf + ((size_t)(b * TT + t0)) * 512 + a;
    const float* al = alpha + h * TT + t0;
    float s = 0.f, sk = 0.f;
#pragma unroll 8
    for (int it = 0; it < CLEN; ++it) {
        float kt = kp[(size_t)it * 512];
        float vt = vp[(size_t)it * 512];
        sk += kt;
        s = fmaf(r, s, al[it] * kt * vt);
    }
    int o = (b * NCHUNK + j) * 512 + a;
    Sloc[o] = s;
    Kloc[o] = sk;
}

// ---------------- scan mid: exclusive prefix across chunks ----------------
__global__ void scanMid(const float* __restrict__ tw,
                        const float* __restrict__ Sloc, const float* __restrict__ Kloc,
                        float* __restrict__ Sin, float* __restrict__ Kin) {
    int idx = blockIdx.x * 256 + threadIdx.x;  // 4096 = B*A
    int a = idx & 511, b = idx >> 9;
    int h = a >> 6;
    float r = tw[h * TT + TT - 2];
    float rL = r;
#pragma unroll
    for (int i = 0; i < 7; ++i) rL *= rL;      // r^128
    float cs = 0.f, ck = 0.f;
#pragma unroll
    for (int j = 0; j < NCHUNK; ++j) {
        int o = (b * NCHUNK + j) * 512 + a;
        Sin[o] = cs;
        Kin[o] = ck;
        cs = fmaf(rL, cs, Sloc[o]);
        ck += Kloc[o];
    }
}

// ---------------- scan phase B: replay with true prefix, emit rwkv (bf16) --------
__global__ void scanB(const float* __restrict__ kbuf, const float* __restrict__ vbuf,
                      const float* __restrict__ rbuf,
                      const float* __restrict__ tw, const float* __restrict__ alpha,
                      const float* __restrict__ beta,
                      const float* __restrict__ Sin, const float* __restrict__ Kin,
                      unsigned short* __restrict__ rwkv) {
    int tid = threadIdx.x;
    int bid = blockIdx.x;
    int ab = bid & 1, j = (bid >> 1) & 15, b = bid >> 5;
    int a = ab * 256 + tid;
    int h = a >> 6;
    float r = tw[h * TT + TT - 2];
    int t0 = j * CLEN;
    size_t base = ((size_t)(b * TT + t0)) * 512 + a;
    const float* al = alpha + h * TT + t0;
    const float* bt = beta + h * TT + t0;
    int o = (b * NCHUNK + j) * 512 + a;
    float s = Sin[o], sk = Kin[o];
#pragma unroll 4
    for (int it = 0; it < CLEN; ++it) {
        float kt = kbuf[base + (size_t)it * 512];
        float vt = vbuf[base + (size_t)it * 512];
        float rt = rbuf[base + (size_t)it * 512];   // already sigmoid'ed
        sk += kt;
        s = fmaf(r, s, al[it] * kt * vt);
        float w = bt[it] * s;
        rwkv[base + (size_t)it * 512] = f2bf(rt * w / sk);
    }
}

extern "C" void kernel_launch(void* const* d_in, const int* in_sizes, int n_in,
                              void* d_out, int out_size, void* d_ws, size_t ws_size,
                              hipStream_t stream) {
    const float* x   = (const float*)d_in[0];
    const float* tw  = (const float*)d_in[1];
    const float* ta  = (const float*)d_in[2];
    const float* tb  = (const float*)d_in[3];
    const float* tg  = (const float*)d_in[4];
    const float* tmk = (const float*)d_in[5];
    const float* tmv = (const float*)d_in[6];
    const float* tmr = (const float*)d_in[7];
    const float* Wk  = (const float*)d_in[8];
    const float* bk  = (const float*)d_in[9];
    const float* Wv  = (const float*)d_in[10];
    const float* bv  = (const float*)d_in[11];
    const float* Wr  = (const float*)d_in[12];
    const float* br  = (const float*)d_in[13];
    const float* Wo  = (const float*)d_in[14];
    const float* bo  = (const float*)d_in[15];

    char* ws = (char*)d_ws;
    unsigned short* Wkb  = (unsigned short*)(ws + 0);
    unsigned short* Wvb  = (unsigned short*)(ws + 524288);
    unsigned short* Wrb  = (unsigned short*)(ws + 1048576);
    unsigned short* Wob  = (unsigned short*)(ws + 1572864);
    unsigned short* Abuf = (unsigned short*)(ws + 2097152);    // 16 MB, reused 4x
    float* kbuf = (float*)(ws + 18874368);                      // 32 MB
    float* vbuf = (float*)(ws + 52428800);                      // 32 MB
    float* rbuf = (float*)(ws + 85983232);                      // 32 MB
    float* Sloc = (float*)(ws + 119537664);
    float* Kloc = (float*)(ws + 119799808);
    float* Sin  = (float*)(ws + 120061952);
    float* Kin  = (float*)(ws + 120324096);

    convert_bf16<<<256, 256, 0, stream>>>(Wk, Wkb);
    convert_bf16<<<256, 256, 0, stream>>>(Wv, Wvb);
    convert_bf16<<<256, 256, 0, stream>>>(Wr, Wrb);
    convert_bf16<<<256, 256, 0, stream>>>(Wo, Wob);

    dim3 ggrid(4, 128);

    mix_kernel<<<8192, 256, 0, stream>>>(x, tmk, Abuf);
    gemm_bt<0><<<ggrid, 256, 0, stream>>>(Abuf, Wkb, bk, kbuf, nullptr);
    mix_kernel<<<8192, 256, 0, stream>>>(x, tmv, Abuf);
    gemm_bt<1><<<ggrid, 256, 0, stream>>>(Abuf, Wvb, bv, vbuf, nullptr);
    mix_kernel<<<8192, 256, 0, stream>>>(x, tmr, Abuf);
    gemm_bt<2><<<ggrid, 256, 0, stream>>>(Abuf, Wrb, br, rbuf, nullptr);

    scanA<<<256, 256, 0, stream>>>(kbuf, vbuf, tw, ta, Sloc, Kloc);
    scanMid<<<16, 256, 0, stream>>>(tw, Sloc, Kloc, Sin, Kin);
    scanB<<<256, 256, 0, stream>>>(kbuf, vbuf, rbuf, tw, ta, tb, Sin, Kin, Abuf);

    gemm_bt<3><<<ggrid, 256, 0, stream>>>(Abuf, Wob, bo, (float*)d_out, tg);
}

// Round 2
// 211.405 us; speedup vs baseline: 1.1722x; 1.1722x over previous
//
#include <hip/hip_runtime.h>
#include <hip/hip_bf16.h>

#define TTLEN 2048
#define NCH   64
#define CLEN  32    // TTLEN / NCH

typedef unsigned short ushort_t;
typedef __attribute__((ext_vector_type(8))) short short8;
typedef __attribute__((ext_vector_type(4))) float f32x4;

__device__ __forceinline__ unsigned short f2bf(float f) {
    __hip_bfloat16 h = __float2bfloat16(f);
    return *reinterpret_cast<unsigned short*>(&h);
}
__device__ __forceinline__ float bf2f(unsigned int u16) {
    union { unsigned int i; float f; } v; v.i = u16 << 16; return v.f;
}

#define GLD_LDS16(gp, lp) __builtin_amdgcn_global_load_lds( \
    (const __attribute__((address_space(1))) void*)(gp),    \
    (__attribute__((address_space(3))) void*)(lp), 16, 0, 0)

// ---------------- weights fp32 -> bf16, all four in one launch ----------------
__global__ void convert4(const float* __restrict__ Wk, const float* __restrict__ Wv,
                         const float* __restrict__ Wr, const float* __restrict__ Wo,
                         ushort_t* __restrict__ Wall, ushort_t* __restrict__ Wob) {
    int m = blockIdx.x >> 8;                       // 0..3
    const float* src = (m == 0) ? Wk : (m == 1) ? Wv : (m == 2) ? Wr : Wo;
    ushort_t* dst = (m == 3) ? Wob : Wall + (size_t)m * 262144;
    int i = (blockIdx.x & 255) * 256 + threadIdx.x;  // group of 4
    float4 v = *(const float4*)(src + (size_t)i * 4);
    union { unsigned short u[4]; uint2 p; } pk;
    pk.u[0] = f2bf(v.x); pk.u[1] = f2bf(v.y); pk.u[2] = f2bf(v.z); pk.u[3] = f2bf(v.w);
    *(uint2*)(dst + (size_t)i * 4) = pk.p;
}

// ------------- time-shift mix: one x read, three bf16 outputs -------------
__global__ void mix3(const float* __restrict__ x,
                     const float* __restrict__ tmk, const float* __restrict__ tmv,
                     const float* __restrict__ tmr,
                     ushort_t* __restrict__ xk, ushort_t* __restrict__ xv,
                     ushort_t* __restrict__ xr) {
    int i   = blockIdx.x * 256 + threadIdx.x;      // group of 4 channels
    int c4  = (i & 127) << 2;
    int row = i >> 7;                              // b*T + t
    int t   = row & (TTLEN - 1);
    float4 xc = *(const float4*)(x + (size_t)row * 512 + c4);
    float4 xp = make_float4(0.f, 0.f, 0.f, 0.f);
    if (t != 0) xp = *(const float4*)(x + (size_t)(row - 1) * 512 + c4);
    size_t o = (size_t)row * 512 + c4;
    union { unsigned short u[4]; uint2 p; } pk;
    {
        float4 tv = *(const float4*)(tmk + c4);
        pk.u[0] = f2bf(xc.x * tv.x + xp.x * (1.f - tv.x));
        pk.u[1] = f2bf(xc.y * tv.y + xp.y * (1.f - tv.y));
        pk.u[2] = f2bf(xc.z * tv.z + xp.z * (1.f - tv.z));
        pk.u[3] = f2bf(xc.w * tv.w + xp.w * (1.f - tv.w));
        *(uint2*)(xk + o) = pk.p;
    }
    {
        float4 tv = *(const float4*)(tmv + c4);
        pk.u[0] = f2bf(xc.x * tv.x + xp.x * (1.f - tv.x));
        pk.u[1] = f2bf(xc.y * tv.y + xp.y * (1.f - tv.y));
        pk.u[2] = f2bf(xc.z * tv.z + xp.z * (1.f - tv.z));
        pk.u[3] = f2bf(xc.w * tv.w + xp.w * (1.f - tv.w));
        *(uint2*)(xv + o) = pk.p;
    }
    {
        float4 tv = *(const float4*)(tmr + c4);
        pk.u[0] = f2bf(xc.x * tv.x + xp.x * (1.f - tv.x));
        pk.u[1] = f2bf(xc.y * tv.y + xp.y * (1.f - tv.y));
        pk.u[2] = f2bf(xc.z * tv.z + xp.z * (1.f - tv.z));
        pk.u[3] = f2bf(xc.w * tv.w + xp.w * (1.f - tv.w));
        *(uint2*)(xr + o) = pk.p;
    }
}

// ---------------- m97-style GEMM, 128x128 tile, BK=64, global_load_lds ----------------
// MODE 0: fused k/v/r (N=1536, A chosen per 512-col band, bf16 out, epilogue per band)
// MODE 1: out-projection (N=512, fp32 out, *gamma[t])
template <int MODE>
__launch_bounds__(256)
__global__ void gemm_m97(const ushort_t* __restrict__ Axk, const ushort_t* __restrict__ Axv,
                         const ushort_t* __restrict__ Axr, const ushort_t* __restrict__ W,
                         const float* __restrict__ b0, const float* __restrict__ b1,
                         const float* __restrict__ b2,
                         ushort_t* __restrict__ o0, ushort_t* __restrict__ o1,
                         ushort_t* __restrict__ o2,
                         float* __restrict__ fout, const float* __restrict__ gamma) {
    __shared__ alignas(16) ushort_t As[128 * 64];
    __shared__ alignas(16) ushort_t Bs[128 * 64];
    const int tid  = threadIdx.x;
    const int lane = tid & 63;
    const int w    = tid >> 6;
    const int wm   = (w >> 1) << 6;
    const int wn   = (w & 1) << 6;
    const int mBlk = blockIdx.y << 7;
    const int nBlk = blockIdx.x << 7;
    const int r16  = lane & 15, q = lane >> 4;
    const int rowInW = lane >> 3, ch = lane & 7;

    const int p = nBlk >> 9;   // projection band (MODE 0)
    const ushort_t* A = (MODE == 1) ? Axk : (p == 0 ? Axk : (p == 1 ? Axv : Axr));

    f32x4 acc[4][4];
#pragma unroll
    for (int a = 0; a < 4; ++a)
#pragma unroll
        for (int b = 0; b < 4; ++b) acc[a][b] = (f32x4){0.f, 0.f, 0.f, 0.f};

    for (int k0 = 0; k0 < 512; k0 += 64) {
        const ushort_t* Ag = A + (size_t)mBlk * 512 + k0;
        const ushort_t* Bg = W + (size_t)nBlk * 512 + k0;
#pragma unroll
        for (int i = 0; i < 4; ++i) {
            int baseRow = w * 32 + i * 8;
            int row = baseRow + rowInW;
            int gch = ch ^ (row & 7);
            GLD_LDS16(Ag + (size_t)row * 512 + gch * 8, &As[baseRow * 64]);
            GLD_LDS16(Bg + (size_t)row * 512 + gch * 8, &Bs[baseRow * 64]);
        }
        asm volatile("s_waitcnt vmcnt(0)" ::: "memory");
        __syncthreads();
#pragma unroll
        for (int s = 0; s < 2; ++s) {
            short8 af[4], bfr[4];
#pragma unroll
            for (int mt = 0; mt < 4; ++mt) {
                int row = wm + mt * 16 + r16;
                af[mt] = *(const short8*)(&As[row * 64 + (((s * 4 + q) ^ (r16 & 7)) << 3)]);
            }
#pragma unroll
            for (int nt = 0; nt < 4; ++nt) {
                int row = wn + nt * 16 + r16;
                bfr[nt] = *(const short8*)(&Bs[row * 64 + (((s * 4 + q) ^ (r16 & 7)) << 3)]);
            }
#pragma unroll
            for (int mt = 0; mt < 4; ++mt)
#pragma unroll
                for (int nt = 0; nt < 4; ++nt)
                    acc[mt][nt] = __builtin_amdgcn_mfma_f32_16x16x32_bf16(
                        af[mt], bfr[nt], acc[mt][nt], 0, 0, 0);
        }
        __syncthreads();
    }

    if (MODE == 0) {
        const float* bias = (p == 0) ? b0 : (p == 1) ? b1 : b2;
        ushort_t* outp = (p == 0) ? o0 : (p == 1) ? o1 : o2;
#pragma unroll
        for (int mt = 0; mt < 4; ++mt) {
#pragma unroll
            for (int nt = 0; nt < 4; ++nt) {
                int nLocal = (nBlk & 511) + wn + nt * 16 + r16;
                float bv = bias[nLocal];
#pragma unroll
                for (int i = 0; i < 4; ++i) {
                    int row = mBlk + wm + mt * 16 + (q << 2) + i;
                    float v = acc[mt][nt][i] + bv;
                    if (p == 0) v = __expf(fminf(fmaxf(v, -60.f), 30.f));
                    else if (p == 2) v = 1.f / (1.f + __expf(-v));
                    outp[(size_t)row * 512 + nLocal] = f2bf(v);
                }
            }
        }
    } else {
#pragma unroll
        for (int mt = 0; mt < 4; ++mt) {
#pragma unroll
            for (int nt = 0; nt < 4; ++nt) {
                int col = nBlk + wn + nt * 16 + r16;
                float bv = b0[col];
#pragma unroll
                for (int i = 0; i < 4; ++i) {
                    int row = mBlk + wm + mt * 16 + (q << 2) + i;
                    float v = (acc[mt][nt][i] + bv) * gamma[row & (TTLEN - 1)];
                    fout[(size_t)row * 512 + col] = v;
                }
            }
        }
    }
}

// ---------------- scan phase A: per-chunk local (S, sum_k), bf16 in ----------------
__global__ void scanA(const ushort_t* __restrict__ kb, const ushort_t* __restrict__ vb,
                      const float* __restrict__ tw, const float* __restrict__ alpha,
                      float* __restrict__ Sloc, float* __restrict__ Kloc) {
    int tid = threadIdx.x;
    int b = blockIdx.x >> 6, j = blockIdx.x & 63;
    int a0 = tid * 2;
    int h = a0 >> 6;
    float r = tw[h * TTLEN + TTLEN - 2];
    int t0 = j * CLEN;
    size_t base = ((size_t)(b * TTLEN + t0)) * 512 + a0;
    const float* al = alpha + h * TTLEN + t0;
    float s0 = 0.f, s1 = 0.f, sk0 = 0.f, sk1 = 0.f;
#pragma unroll 8
    for (int it = 0; it < CLEN; ++it) {
        unsigned int kk = *(const unsigned int*)(kb + base + (size_t)it * 512);
        unsigned int vv = *(const unsigned int*)(vb + base + (size_t)it * 512);
        float kf0 = bf2f(kk & 0xffff), kf1 = bf2f(kk >> 16);
        float vf0 = bf2f(vv & 0xffff), vf1 = bf2f(vv >> 16);
        float av = al[it];
        sk0 += kf0; sk1 += kf1;
        s0 = fmaf(r, s0, av * kf0 * vf0);
        s1 = fmaf(r, s1, av * kf1 * vf1);
    }
    int o = (b * NCH + j) * 512 + a0;
    Sloc[o] = s0; Sloc[o + 1] = s1;
    Kloc[o] = sk0; Kloc[o + 1] = sk1;
}

// ---------------- scan mid: exclusive prefix across chunks ----------------
__global__ void scanMid(const float* __restrict__ tw,
                        const float* __restrict__ Sloc, const float* __restrict__ Kloc,
                        float* __restrict__ Sin, float* __restrict__ Kin) {
    int idx = blockIdx.x * 256 + threadIdx.x;   // 4096 = B*A
    int a = idx & 511, b = idx >> 9;
    int h = a >> 6;
    float r = tw[h * TTLEN + TTLEN - 2];
    float rL = r;
#pragma unroll
    for (int i = 0; i < 5; ++i) rL *= rL;       // r^32
    float cs = 0.f, ck = 0.f;
#pragma unroll
    for (int j = 0; j < NCH; ++j) {
        int o = (b * NCH + j) * 512 + a;
        Sin[o] = cs; Kin[o] = ck;
        cs = fmaf(rL, cs, Sloc[o]);
        ck += Kloc[o];
    }
}

// ---------------- scan phase B: replay with true prefix, emit rwkv bf16 ----------------
__global__ void scanB(const ushort_t* __restrict__ kb, const ushort_t* __restrict__ vb,
                      const ushort_t* __restrict__ rb,
                      const float* __restrict__ tw, const float* __restrict__ alpha,
                      const float* __restrict__ beta,
                      const float* __restrict__ Sin, const float* __restrict__ Kin,
                      ushort_t* __restrict__ rwkv) {
    int tid = threadIdx.x;
    int b = blockIdx.x >> 6, j = blockIdx.x & 63;
    int a0 = tid * 2;
    int h = a0 >> 6;
    float r = tw[h * TTLEN + TTLEN - 2];
    int t0 = j * CLEN;
    size_t base = ((size_t)(b * TTLEN + t0)) * 512 + a0;
    const float* al = alpha + h * TTLEN + t0;
    const float* bt = beta + h * TTLEN + t0;
    int o = (b * NCH + j) * 512 + a0;
    float s0 = Sin[o], s1 = Sin[o + 1], sk0 = Kin[o], sk1 = Kin[o + 1];
#pragma unroll 4
    for (int it = 0; it < CLEN; ++it) {
        unsigned int kk = *(const unsigned int*)(kb + base + (size_t)it * 512);
        unsigned int vv = *(const unsigned int*)(vb + base + (size_t)it * 512);
        unsigned int rr = *(const unsigned int*)(rb + base + (size_t)it * 512);
        float kf0 = bf2f(kk & 0xffff), kf1 = bf2f(kk >> 16);
        float vf0 = bf2f(vv & 0xffff), vf1 = bf2f(vv >> 16);
        float rf0 = bf2f(rr & 0xffff), rf1 = bf2f(rr >> 16);
        float av = al[it], btv = bt[it];
        sk0 += kf0; sk1 += kf1;
        s0 = fmaf(r, s0, av * kf0 * vf0);
        s1 = fmaf(r, s1, av * kf1 * vf1);
        float w0 = btv * s0, w1 = btv * s1;
        unsigned int outw = ((unsigned int)f2bf(rf1 * w1 / sk1) << 16) | f2bf(rf0 * w0 / sk0);
        *(unsigned int*)(rwkv + base + (size_t)it * 512) = outw;
    }
}

extern "C" void kernel_launch(void* const* d_in, const int* in_sizes, int n_in,
                              void* d_out, int out_size, void* d_ws, size_t ws_size,
                              hipStream_t stream) {
    const float* x   = (const float*)d_in[0];
    const float* tw  = (const float*)d_in[1];
    const float* ta  = (const float*)d_in[2];
    const float* tb  = (const float*)d_in[3];
    const float* tg  = (const float*)d_in[4];
    const float* tmk = (const float*)d_in[5];
    const float* tmv = (const float*)d_in[6];
    const float* tmr = (const float*)d_in[7];
    const float* Wk  = (const float*)d_in[8];
    const float* bk  = (const float*)d_in[9];
    const float* Wv  = (const float*)d_in[10];
    const float* bv  = (const float*)d_in[11];
    const float* Wr  = (const float*)d_in[12];
    const float* br  = (const float*)d_in[13];
    const float* Wo  = (const float*)d_in[14];
    const float* bo  = (const float*)d_in[15];

    char* ws = (char*)d_ws;
    ushort_t* Wall = (ushort_t*)(ws + 0);            // [1536][512] bf16 (Wk;Wv;Wr)
    ushort_t* Wob  = (ushort_t*)(ws + 1572864);      // [512][512] bf16
    ushort_t* xk   = (ushort_t*)(ws + 2097152);      // 16.78 MB each
    ushort_t* xv   = (ushort_t*)(ws + 18874368);
    ushort_t* xr   = (ushort_t*)(ws + 35651584);
    ushort_t* kb   = (ushort_t*)(ws + 52428800);
    ushort_t* vb   = (ushort_t*)(ws + 69206016);
    ushort_t* rb   = (ushort_t*)(ws + 85983232);
    ushort_t* rwkv = xk;                             // xk dead after gemm<0>
    float* Sloc = (float*)(ws + 102760448);          // 1 MB each
    float* Kloc = (float*)(ws + 103809024);
    float* Sin  = (float*)(ws + 104857600);
    float* Kin  = (float*)(ws + 105906176);

    convert4<<<1024, 256, 0, stream>>>(Wk, Wv, Wr, Wo, Wall, Wob);
    mix3<<<8192, 256, 0, stream>>>(x, tmk, tmv, tmr, xk, xv, xr);

    gemm_m97<0><<<dim3(12, 128), 256, 0, stream>>>(xk, xv, xr, Wall, bk, bv, br,
                                                   kb, vb, rb, nullptr, nullptr);

    scanA<<<512, 256, 0, stream>>>(kb, vb, tw, ta, Sloc, Kloc);
    scanMid<<<16, 256, 0, stream>>>(tw, Sloc, Kloc, Sin, Kin);
    scanB<<<512, 256, 0, stream>>>(kb, vb, rb, tw, ta, tb, Sin, Kin, rwkv);

    gemm_m97<1><<<dim3(4, 128), 256, 0, stream>>>(rwkv, nullptr, nullptr, Wob, bo, nullptr,
                                                  nullptr, nullptr, nullptr, nullptr,
                                                  (float*)d_out, tg);
}